// Round 6
// baseline (278.098 us; speedup 1.0000x reference)
//
#include <hip/hip_runtime.h>
#include <stdint.h>

// Word2MatEncoder: out[b] = prod_{s=0..63} table[sent[b,s]]  (28x28 fp32 chain)
//
// R6: R5 was stall-bound at 0.89 waves/SIMD (VALUBusy 30%; FMA model = the
// whole 30%). Same kernel body (proven spill-free skeleton: flat macros,
// named-array ping-pong, global_load_lds staging, no inline asm); the change
// is decomposition: P=8 segments of 8 per item -> 16384 tasks -> 1821 blocks
// = 1.8 waves/SIMD, so a second wave's FMAs hide the per-step vmcnt(0) DMA
// drain and lgkm bubbles. ws tiers: P=8 (51.4 MB) -> P=4 (25.7 MB) -> P=1.
// Structural floor of this read pattern: LDS delivery ~49 us + overlap slack;
// FMA floor 35 us.
// fp32 throughout (no fp32 MFMA on CDNA4; bf16 error compounds over 63 muls).

#define D 28
#define EMB 784
#define SEQ 64
#define NITEMS 2048
#define LPI 7            // lanes per task
#define IPW 9            // tasks per wave (63 of 64 lanes active)
#define RPL 4            // rows of the running product per lane
#define NCHUNK 28        // DMA chunks per matrix-set (1 row x 9 slots each)
#define CHUNK_F 256      // floats per chunk (64 lanes x 16B)
#define BUF_F (NCHUNK * CHUNK_F)  // 7168 floats = 28672 B

typedef __attribute__((address_space(3))) uint32_t lds_u32;
typedef const __attribute__((address_space(1))) uint32_t glb_u32;

// Stage one matrix per slot into LDS. glane = matrix base + rl*16B (per lane);
// chunk t pulls row t (bytes [t*112, t*112+16) per lane) of each slot's matrix.
__device__ __forceinline__ void dma_mat(const float* glane, float* lds0) {
#pragma unroll
  for (int t = 0; t < NCHUNK; ++t)
    __builtin_amdgcn_global_load_lds((glb_u32*)(glane + t * D),
                                     (lds_u32*)(lds0 + t * CHUNK_F), 16, 0, 0);
}

// Cc = Aa @ M   (M staged in LDS at Bs with the chunk layout above)
#define MATMUL(Aa, Cc)                                                         \
  do {                                                                         \
    _Pragma("unroll") for (int k = 0; k < D; ++k) {                            \
      _Pragma("unroll") for (int jv = 0; jv < 7; ++jv) {                       \
        float4 m = *(const float4*)(Bs + k * CHUNK_F + 4 * jv);                \
        _Pragma("unroll") for (int r = 0; r < RPL; ++r) {                      \
          float a = Aa[r][k];                                                  \
          if (k == 0) {                                                        \
            Cc[r][4 * jv + 0] = a * m.x;                                       \
            Cc[r][4 * jv + 1] = a * m.y;                                       \
            Cc[r][4 * jv + 2] = a * m.z;                                       \
            Cc[r][4 * jv + 3] = a * m.w;                                       \
          } else {                                                             \
            Cc[r][4 * jv + 0] = fmaf(a, m.x, Cc[r][4 * jv + 0]);               \
            Cc[r][4 * jv + 1] = fmaf(a, m.y, Cc[r][4 * jv + 1]);               \
            Cc[r][4 * jv + 2] = fmaf(a, m.z, Cc[r][4 * jv + 2]);               \
            Cc[r][4 * jv + 3] = fmaf(a, m.w, Cc[r][4 * jv + 3]);               \
          }                                                                    \
        }                                                                      \
      }                                                                        \
    }                                                                          \
  } while (0)

// One chain step: wait staged matrix, multiply, then DMA the next one.
#define STEP(Aa, Cc)                                                           \
  do {                                                                         \
    __builtin_amdgcn_s_waitcnt(0x0f70); /* vmcnt(0): matrix landed */          \
    __syncthreads();                                                           \
    MATMUL(Aa, Cc);                                                            \
    __syncthreads(); /* all LDS reads drained before overwrite */              \
    if (s + 1 < SEG_LEN) {                                                     \
      dma_mat(gn, lds);                                                        \
      int nn = (s + 2 < SEG_LEN) ? s + 2 : SEG_LEN - 1;                        \
      gn = glane(nn);                                                          \
    }                                                                          \
    ++s;                                                                       \
  } while (0)

// Product of SEG_LEN consecutive matrices (SEG_LEN-1 odd -> result in A1).
// GATHER: matrices are table[sp[s]]; else dense at src + (task*SEG_LEN+s)*EMB.
template <int SEG_LEN, int PSEG, bool GATHER>
__global__ __launch_bounds__(64, 1) void chain_kernel(
    const float* __restrict__ src, const int* __restrict__ sent,
    float* __restrict__ dst, int ntask) {
  __shared__ __align__(16) float lds[BUF_F];

  const int lane = threadIdx.x;
  int slot = lane / LPI;
  int rl = lane - slot * LPI;
  if (slot >= IPW) { slot = IPW - 1; rl = LPI - 1; }  // lane 63 mirrors lane 62
  int task = blockIdx.x * IPW + slot;
  if (task >= ntask) task = ntask - 1;  // tail duplicates (same values, benign)

  const int* sp = nullptr;
  if (GATHER) {
    const int item = task / PSEG;
    const int seg = task - item * PSEG;
    sp = sent + item * SEQ + seg * SEG_LEN;
  }
  auto glane = [&](int s) -> const float* {
    const float* m = GATHER ? src + (size_t)sp[s] * EMB
                            : src + ((size_t)task * SEG_LEN + s) * EMB;
    return m + rl * 4;  // this lane's 16B slice of each row
  };

  float A0[RPL][D], A1[RPL][D];

  // A0 = this lane's rows (rl*4 .. rl*4+3) of the first matrix (direct loads)
  {
    const float* m0 = GATHER ? src + (size_t)sp[0] * EMB
                             : src + (size_t)task * SEG_LEN * EMB;
#pragma unroll
    for (int r = 0; r < RPL; ++r) {
      const float* rp = m0 + (rl * RPL + r) * D;
#pragma unroll
      for (int jv = 0; jv < 7; ++jv) {
        float4 v = *(const float4*)(rp + 4 * jv);
        A0[r][4 * jv + 0] = v.x;
        A0[r][4 * jv + 1] = v.y;
        A0[r][4 * jv + 2] = v.z;
        A0[r][4 * jv + 3] = v.w;
      }
    }
  }

  // stage matrix 1; prefetch pointer for matrix 2
  dma_mat(glane(1), lds);
  const float* gn = glane(SEG_LEN > 2 ? 2 : 1);
  const float* Bs = lds + slot * (LPI * 4);  // slot*28 floats

  int s = 1;
#pragma unroll 1
  for (int p = 0; p < (SEG_LEN - 1) / 2; ++p) {
    STEP(A0, A1);
    STEP(A1, A0);
  }
  STEP(A0, A1);  // final step (SEG_LEN-1 is odd) -> result in A1

  // store
  {
    float* op = dst + (size_t)task * EMB;
#pragma unroll
    for (int r = 0; r < RPL; ++r) {
      float* rp = op + (rl * RPL + r) * D;
#pragma unroll
      for (int jv = 0; jv < 7; ++jv) {
        *(float4*)(rp + 4 * jv) =
            make_float4(A1[r][4 * jv + 0], A1[r][4 * jv + 1],
                        A1[r][4 * jv + 2], A1[r][4 * jv + 3]);
      }
    }
  }
}

extern "C" void kernel_launch(void* const* d_in, const int* in_sizes, int n_in,
                              void* d_out, int out_size, void* d_ws, size_t ws_size,
                              hipStream_t stream) {
  const float* table = (const float*)d_in[0];
  const int* sent = (const int*)d_in[1];
  float* out = (float*)d_out;

  const size_t need8 = (size_t)NITEMS * 8 * EMB * sizeof(float);  // 51.4 MB
  const size_t need4 = (size_t)NITEMS * 4 * EMB * sizeof(float);  // 25.7 MB
  if (ws_size >= need8) {
    float* p = (float*)d_ws;
    // phase 1: 8 segments of 8 per item -> 16384 partials -> 1.8 waves/SIMD
    const int ntask1 = NITEMS * 8;
    chain_kernel<8, 8, true><<<(ntask1 + IPW - 1) / IPW, 64, 0, stream>>>(
        table, sent, p, ntask1);
    // phase 2: chain each item's 8 partials -> d_out (7 steps)
    chain_kernel<8, 1, false><<<(NITEMS + IPW - 1) / IPW, 64, 0, stream>>>(
        p, nullptr, out, NITEMS);
  } else if (ws_size >= need4) {
    float* p = (float*)d_ws;
    // phase 1: 4 segments of 16 per item -> 8192 partials
    const int ntask1 = NITEMS * 4;
    chain_kernel<16, 4, true><<<(ntask1 + IPW - 1) / IPW, 64, 0, stream>>>(
        table, sent, p, ntask1);
    // phase 2: chain each item's 4 partials -> d_out
    chain_kernel<4, 1, false><<<(NITEMS + IPW - 1) / IPW, 64, 0, stream>>>(
        p, nullptr, out, NITEMS);
  } else {
    // fallback: direct 64-long chain per item straight into d_out
    chain_kernel<64, 1, true><<<(NITEMS + IPW - 1) / IPW, 64, 0, stream>>>(
        table, sent, out, NITEMS);
  }
}